// Round 7
// baseline (717.460 us; speedup 1.0000x reference)
//
#include <hip/hip_runtime.h>

#define NEGF (-1e30f)

namespace {

constexpr int B = 4, T = 512, L = 64, U = 65, V = 1024;

__device__ __forceinline__ float lse2(float a, float b) {
    // logaddexp; safe when one/both operands are ~-1e30 (exp underflows to 0)
    float m = fmaxf(a, b);
    float d = fminf(a, b) - m;
    return m + __logf(1.0f + __expf(d));
}

// --- DPP helpers: cross-lane without the LDS pipe (ds_permute ~120cy) ------
// quad_perm [1,0,3,2]=0xB1 (xor1), [2,3,0,1]=0x4E (xor2),
// ROW_HALF_MIRROR=0x141 (4<->4 within 8), ROW_MIRROR=0x140 (8<->8),
// WAVE_SHR1=0x138 (lane i <- lane i-1). All VALU, ~2-4cy each.
__device__ __forceinline__ float dpp_bcast_op_max(float x) {
    x = fmaxf(x, __int_as_float(__builtin_amdgcn_update_dpp(0, __float_as_int(x), 0xB1, 0xF, 0xF, true)));
    x = fmaxf(x, __int_as_float(__builtin_amdgcn_update_dpp(0, __float_as_int(x), 0x4E, 0xF, 0xF, true)));
    x = fmaxf(x, __int_as_float(__builtin_amdgcn_update_dpp(0, __float_as_int(x), 0x141, 0xF, 0xF, true)));
    x = fmaxf(x, __int_as_float(__builtin_amdgcn_update_dpp(0, __float_as_int(x), 0x140, 0xF, 0xF, true)));
    x = fmaxf(x, __shfl_xor(x, 16, 64));   // cross-row: LDS swizzle (2 only)
    x = fmaxf(x, __shfl_xor(x, 32, 64));
    return x;
}
__device__ __forceinline__ float dpp_bcast_op_sum(float x) {
    x += __int_as_float(__builtin_amdgcn_update_dpp(0, __float_as_int(x), 0xB1, 0xF, 0xF, true));
    x += __int_as_float(__builtin_amdgcn_update_dpp(0, __float_as_int(x), 0x4E, 0xF, 0xF, true));
    x += __int_as_float(__builtin_amdgcn_update_dpp(0, __float_as_int(x), 0x141, 0xF, 0xF, true));
    x += __int_as_float(__builtin_amdgcn_update_dpp(0, __float_as_int(x), 0x140, 0xF, 0xF, true));
    x += __shfl_xor(x, 16, 64);
    x += __shfl_xor(x, 32, 64);
    return x;
}

__device__ __forceinline__ float dpp_shr1(float x) {
    return __int_as_float(__builtin_amdgcn_update_dpp(
        0, __float_as_int(x), 0x138, 0xF, 0xF, true));
}

// ---------------------------------------------------------------------------
// Kernel 1: per-(b,t,u) log-softmax terms. One wave per row of V=1024 floats.
// UNCHANGED (control variable — this round only changes k2).
// ---------------------------------------------------------------------------
__global__ __launch_bounds__(256) void rna_lse_kernel(
    const float* __restrict__ logits, const int* __restrict__ targets,
    const int* __restrict__ fbank_len, const int* __restrict__ text_len,
    float* __restrict__ lpb, float* __restrict__ lpl) {
    const int lane = threadIdx.x & 63;
    const int row  = blockIdx.x * 4 + (threadIdx.x >> 6);   // (b,t,u) flat
    const int u  = row % U;
    const int bt = row / U;
    const int t  = bt % T;
    const int b  = bt / T;

    const int fb = fbank_len[b];
    const int tl = text_len[b];
    if (t >= fb || u > tl || u > t + 1 || (tl - u) > (fb - t)) return;

    const float*  p  = logits + (size_t)row * V;
    const float4* p4 = (const float4*)p;
    float4 v0 = p4[lane];
    float4 v1 = p4[lane + 64];
    float4 v2 = p4[lane + 128];
    float4 v3 = p4[lane + 192];

    float m = fmaxf(fmaxf(fmaxf(v0.x, v0.y), fmaxf(v0.z, v0.w)),
              fmaxf(fmaxf(fmaxf(v1.x, v1.y), fmaxf(v1.z, v1.w)),
              fmaxf(fmaxf(fmaxf(v2.x, v2.y), fmaxf(v2.z, v2.w)),
                    fmaxf(fmaxf(v3.x, v3.y), fmaxf(v3.z, v3.w)))));
    m = dpp_bcast_op_max(m);

    float s = __expf(v0.x - m) + __expf(v0.y - m) + __expf(v0.z - m) + __expf(v0.w - m)
            + __expf(v1.x - m) + __expf(v1.y - m) + __expf(v1.z - m) + __expf(v1.w - m)
            + __expf(v2.x - m) + __expf(v2.y - m) + __expf(v2.z - m) + __expf(v2.w - m)
            + __expf(v3.x - m) + __expf(v3.y - m) + __expf(v3.z - m) + __expf(v3.w - m);
    s = dpp_bcast_op_sum(s);

    if (lane == 0) {
        float lse = m + __logf(s);
        lpb[(b * U + u) * T + t] = v0.x - lse;
        if (u < L) {
            int tgt = targets[b * L + u];
            lpl[(b * U + u + 1) * T + t] = p[tgt] - lse;   // L1-warm reload
        }
    }
}

// ---------------------------------------------------------------------------
// Kernel 2: forward lattice DP.
//  * 4 blocks (one per batch), 1 wave each -> 4 CUs pull in parallel (4x the
//    single-CU remote-L2/L3 bandwidth of the old 1-block version).
//  * Main loop processes only FULL groups of G=32: no data-dependent break
//    inside the unrolled body, so every array index is compile-time constant
//    (guards against runtime-indexed arrays spilling to scratch, rule #20).
//    Tail (< 32 steps) uses per-step scalar loads with no arrays at all.
//  * G=32 -> ~1600 cy compute per group covers ~900 cy remote-load latency
//    with one-group-ahead prefetch.
//  * Writes per-batch partial result; tiny k3 does the final mean.
// ---------------------------------------------------------------------------
__global__ __launch_bounds__(64, 1) void rna_dp_kernel(
    const float* __restrict__ lpb, const float* __restrict__ lpl,
    const int* __restrict__ fbank_len, const int* __restrict__ text_len,
    float* __restrict__ partial) {
    const int lane = threadIdx.x;    // 0..63
    const int b    = blockIdx.x;     // 0..3
    const int fb   = fbank_len[b];
    const int tl   = text_len[b];

    const float* pbR   = lpb + (b * U + lane) * T;
    const float* plR   = lpl + (b * U + lane) * T;   // shifted label lp (row 0 unused)
    const float* pbR64 = lpb + (b * U + 64) * T;     // wave-uniform -> broadcast
    const float* plR64 = lpl + (b * U + 64) * T;

    float alpha   = (lane == 0) ? 0.0f : NEGF;
    float alpha64 = NEGF;                            // only lane 63's copy meaningful

    constexpr int G = 32;
    float cb[G], cl[G], cb64[G], cl64[G];
#pragma unroll
    for (int q = 0; q < G / 4; ++q) {
        float4 a  = *(const float4*)(pbR   + 4 * q);
        float4 c  = *(const float4*)(plR   + 4 * q);
        float4 e  = *(const float4*)(pbR64 + 4 * q);
        float4 g4 = *(const float4*)(plR64 + 4 * q);
        cb[4*q+0]=a.x;  cb[4*q+1]=a.y;  cb[4*q+2]=a.z;  cb[4*q+3]=a.w;
        cl[4*q+0]=c.x;  cl[4*q+1]=c.y;  cl[4*q+2]=c.z;  cl[4*q+3]=c.w;
        cb64[4*q+0]=e.x;  cb64[4*q+1]=e.y;  cb64[4*q+2]=e.z;  cb64[4*q+3]=e.w;
        cl64[4*q+0]=g4.x; cl64[4*q+1]=g4.y; cl64[4*q+2]=g4.z; cl64[4*q+3]=g4.w;
    }

    const int nFull = fb / G;                        // >= 12 (fb >= 384)
    for (int g = 0; g < nFull; ++g) {
        const int t0 = g * G;
        float nb[G], nl[G], nb64[G], nl64[G];
        const bool pf = (g + 1 < nFull);
        if (pf) {
            const int tn = t0 + G;                   // reads tn..tn+31 <= 511, in-bounds
#pragma unroll
            for (int q = 0; q < G / 4; ++q) {
                float4 a  = *(const float4*)(pbR   + tn + 4 * q);
                float4 c  = *(const float4*)(plR   + tn + 4 * q);
                float4 e  = *(const float4*)(pbR64 + tn + 4 * q);
                float4 g4 = *(const float4*)(plR64 + tn + 4 * q);
                nb[4*q+0]=a.x;  nb[4*q+1]=a.y;  nb[4*q+2]=a.z;  nb[4*q+3]=a.w;
                nl[4*q+0]=c.x;  nl[4*q+1]=c.y;  nl[4*q+2]=c.z;  nl[4*q+3]=c.w;
                nb64[4*q+0]=e.x;  nb64[4*q+1]=e.y;  nb64[4*q+2]=e.z;  nb64[4*q+3]=e.w;
                nl64[4*q+0]=g4.x; nl64[4*q+1]=g4.y; nl64[4*q+2]=g4.z; nl64[4*q+3]=g4.w;
            }
        }
#pragma unroll
        for (int j = 0; j < G; ++j) {                // full group: no break
            const int t = t0 + j;
            float ap   = dpp_shr1(alpha);            // alpha[u-1], VALU lane shift
            float stay = alpha + cb[j];
            float move = (lane == 0) ? NEGF : (ap + cl[j]);
            float na   = lse2(stay, move);
            // state 64: uses OLD alpha[63] (lane-local, pre-update).
            float stay64 = alpha64 + cb64[j];
            float move64 = alpha + cl64[j];
            alpha64 = lse2(stay64, move64);
            alpha   = na;
            // diagonal clamp: kills trapezoid-skipped poison; exact as before.
            if (lane > t + 1) alpha = NEGF;
            if (t + 1 < 64)   alpha64 = NEGF;
        }
        if (pf) {
#pragma unroll
            for (int j = 0; j < G; ++j) {
                cb[j] = nb[j]; cl[j] = nl[j]; cb64[j] = nb64[j]; cl64[j] = nl64[j];
            }
        }
    }

    // tail: < G steps, per-step scalar loads (no arrays -> no scratch risk)
    for (int t = nFull * G; t < fb; ++t) {
        float bj  = pbR[t];
        float lj  = plR[t];
        float b64 = pbR64[t];
        float l64 = plR64[t];
        float ap   = dpp_shr1(alpha);
        float stay = alpha + bj;
        float move = (lane == 0) ? NEGF : (ap + lj);
        float na   = lse2(stay, move);
        float stay64 = alpha64 + b64;
        float move64 = alpha + l64;
        alpha64 = lse2(stay64, move64);
        alpha   = na;
        if (lane > t + 1) alpha = NEGF;
        if (t + 1 < 64)   alpha64 = NEGF;
    }

    float ans = (tl < 64) ? __shfl(alpha, tl, 64) : __shfl(alpha64, 63, 64);
    if (lane == 0) partial[b] = ans;
}

// ---------------------------------------------------------------------------
// Kernel 3: final mean over the 4 per-batch partials (same summation order
// as the old single-block epilogue -> bit-identical result).
// ---------------------------------------------------------------------------
__global__ void rna_sum_kernel(const float* __restrict__ partial,
                               float* __restrict__ out) {
    out[0] = -(partial[0] + partial[1] + partial[2] + partial[3]) * (1.0f / B);
}

} // namespace

extern "C" void kernel_launch(void* const* d_in, const int* in_sizes, int n_in,
                              void* d_out, int out_size, void* d_ws, size_t ws_size,
                              hipStream_t stream) {
    const float* logits  = (const float*)d_in[0];
    const int*   targets = (const int*)d_in[1];
    const int*   fbl     = (const int*)d_in[2];
    const int*   txl     = (const int*)d_in[3];
    float* lpb     = (float*)d_ws;                 // [B][U][T]
    float* lpl     = lpb + (size_t)B * U * T;      // [B][U][T]
    float* partial = lpl + (size_t)B * U * T;      // [B] per-batch log-lik
    float* out     = (float*)d_out;

    const int rows = B * T * U;                    // 133,120 = 33,280 blocks * 4 waves
    rna_lse_kernel<<<rows / 4, 256, 0, stream>>>(logits, targets, fbl, txl, lpb, lpl);
    rna_dp_kernel<<<B, 64, 0, stream>>>(lpb, lpl, fbl, txl, partial);
    rna_sum_kernel<<<1, 1, 0, stream>>>(partial, out);
}